// Round 1
// baseline (92.157 us; speedup 1.0000x reference)
//
#include <hip/hip_runtime.h>
#include <math.h>

#define NPIX 784
#define NCLS 10
#define ROWS_PER_BLOCK 16

// Prep: Tq[q] = sum_l theta[l, w(q)] ; Wp[k*784+q] = W[k*784 + f(q)]
// where pixel q=(i,j): w=(i&1)*2+(j&1), f=((i>>1)*14+(j>>1))*4+w.
__global__ void quanv_prep_kernel(const float* __restrict__ theta,
                                  const float* __restrict__ W,
                                  float* __restrict__ Wp,
                                  float* __restrict__ Tq) {
    __shared__ float Tsum[4];
    int tid = threadIdx.x;
    if (tid < 4) Tsum[tid] = theta[tid] + theta[4 + tid] + theta[8 + tid];
    __syncthreads();
    for (int idx = tid; idx < NCLS * NPIX; idx += blockDim.x) {
        int k = idx / NPIX;
        int q = idx - k * NPIX;
        int i = q / 28, j = q - i * 28;
        int f = (((i >> 1) * 14 + (j >> 1)) << 2) + ((i & 1) * 2 + (j & 1));
        Wp[idx] = W[k * NPIX + f];
    }
    for (int q = tid; q < NPIX; q += blockDim.x) {
        int i = q / 28, j = q - i * 28;
        Tq[q] = Tsum[(i & 1) * 2 + (j & 1)];
    }
}

__global__ __launch_bounds__(256)
void quanv_main_kernel(const float* __restrict__ x,
                       const float* __restrict__ Wp,
                       const float* __restrict__ Tq,
                       const float* __restrict__ bias,
                       float* __restrict__ out, int B) {
    __shared__ float Wl[NCLS * NPIX];   // 30.6 KB
    __shared__ float Tl[NPIX];          // 3.1 KB
    int tid = threadIdx.x;
    for (int idx = tid; idx < NCLS * NPIX; idx += 256) Wl[idx] = Wp[idx];
    for (int idx = tid; idx < NPIX; idx += 256) Tl[idx] = Tq[idx];
    __syncthreads();

    int tx = tid & 15;                       // 16 lanes per row
    int row = blockIdx.x * ROWS_PER_BLOCK + (tid >> 4);

    float acc[NCLS];
#pragma unroll
    for (int k = 0; k < NCLS; ++k) acc[k] = 0.f;

    if (row < B) {
        const float* xr = x + (size_t)row * NPIX;
#pragma unroll
        for (int s = 0; s < 13; ++s) {
            int p = (tx + (s << 4)) << 2;    // float4 granularity, 196 float4/row
            if (p < NPIX) {
                float4 xv = *reinterpret_cast<const float4*>(xr + p);
                float4 tv = *reinterpret_cast<const float4*>(&Tl[p]);
                float f0 = __cosf(xv.x + tv.x);
                float f1 = __cosf(xv.y + tv.y);
                float f2 = __cosf(xv.z + tv.z);
                float f3 = __cosf(xv.w + tv.w);
#pragma unroll
                for (int k = 0; k < NCLS; ++k) {
                    float4 wv = *reinterpret_cast<const float4*>(&Wl[k * NPIX + p]);
                    acc[k] += f0 * wv.x + f1 * wv.y + f2 * wv.z + f3 * wv.w;
                }
            }
        }
    }

    // reduce over the 16 lanes of this row (xor masks stay within 16-group)
#pragma unroll
    for (int k = 0; k < NCLS; ++k) {
        float v = acc[k];
        v += __shfl_xor(v, 1);
        v += __shfl_xor(v, 2);
        v += __shfl_xor(v, 4);
        v += __shfl_xor(v, 8);
        acc[k] = v;
    }

    if (tx == 0 && row < B) {
        float logits[NCLS];
        float m = -1e30f;
#pragma unroll
        for (int k = 0; k < NCLS; ++k) {
            logits[k] = acc[k] + bias[k];
            m = fmaxf(m, logits[k]);
        }
        float sum = 0.f;
#pragma unroll
        for (int k = 0; k < NCLS; ++k) sum += expf(logits[k] - m);
        float lse = m + logf(sum);
#pragma unroll
        for (int k = 0; k < NCLS; ++k) out[row * NCLS + k] = logits[k] - lse;
    }
}

extern "C" void kernel_launch(void* const* d_in, const int* in_sizes, int n_in,
                              void* d_out, int out_size, void* d_ws, size_t ws_size,
                              hipStream_t stream) {
    const float* x     = (const float*)d_in[0];
    const float* theta = (const float*)d_in[1];
    const float* W     = (const float*)d_in[2];
    const float* bias  = (const float*)d_in[3];
    float* out = (float*)d_out;

    float* Wp = (float*)d_ws;            // 7840 floats
    float* Tq = Wp + NCLS * NPIX;        // 784 floats

    int B = in_sizes[0] / NPIX;          // 8192

    quanv_prep_kernel<<<1, 256, 0, stream>>>(theta, W, Wp, Tq);
    int grid = (B + ROWS_PER_BLOCK - 1) / ROWS_PER_BLOCK;
    quanv_main_kernel<<<grid, 256, 0, stream>>>(x, Wp, Tq, bias, out, B);
}

// Round 2
// 80.884 us; speedup vs baseline: 1.1394x; 1.1394x over previous
//
#include <hip/hip_runtime.h>
#include <math.h>

#define NPIX 784
#define NCLS 10
#define ROWS 8            // rows per block
#define LPR 32            // lanes per row
#define BLOCK 256

// Fully fused: per-block builds permuted W + per-pixel angle offsets in LDS,
// then computes feats = cos(x + T), logits = feats @ Wp^T + b, log_softmax.
// Circuit identity: all gates are RY on independent wires, RY compose
// additively, so <Z_w> = cos(x_w + sum_l theta[l][w]).
__global__ __launch_bounds__(256)
void quanv_fused_kernel(const float* __restrict__ x,
                        const float* __restrict__ theta,
                        const float* __restrict__ W,
                        const float* __restrict__ bias,
                        float* __restrict__ out) {
    __shared__ float Wl[NCLS * NPIX];   // 30.6 KB, pixel-order permuted
    __shared__ float Tl[NPIX];          // 3.1 KB
    int tid = threadIdx.x;

    // ---- stage W (float4 global reads, b64 LDS scatter per 2x2 patch) ----
    // W[k][f], f = patch*4 + w, w = (i&1)*2 + (j&1); a float4 at f=patch*4
    // covers wires 0..3 of one patch -> pixels (2pr,2pc),(2pr,2pc+1),
    // (2pr+1,2pc),(2pr+1,2pc+1).
    for (int idx4 = tid; idx4 < (NCLS * NPIX) / 4; idx4 += BLOCK) {
        float4 wv = reinterpret_cast<const float4*>(W)[idx4];
        int idx = idx4 << 2;
        int k = idx / NPIX;
        int p = idx - k * NPIX;
        int patch = p >> 2;
        int pr = patch / 14, pc = patch - pr * 14;
        int q0 = (pr * 28 + pc) * 2;
        float* dst = &Wl[k * NPIX + q0];
        dst[0]  = wv.x;  dst[1]  = wv.y;
        dst[28] = wv.z;  dst[29] = wv.w;
    }
    // ---- per-pixel angle offset T[q] = sum_l theta[l][w(q)] ----
    float t0 = theta[0] + theta[4] + theta[8];
    float t1 = theta[1] + theta[5] + theta[9];
    float t2 = theta[2] + theta[6] + theta[10];
    float t3 = theta[3] + theta[7] + theta[11];
    for (int q = tid; q < NPIX; q += BLOCK) {
        int i = q / 28;
        int j = q - i * 28;
        float ta = (i & 1) ? t2 : t0;
        float tb = (i & 1) ? t3 : t1;
        Tl[q] = (j & 1) ? tb : ta;
    }
    __syncthreads();

    // ---- compute: 32 lanes per row, 8 rows per block ----
    int tx = tid & (LPR - 1);
    int row = blockIdx.x * ROWS + (tid >> 5);
    const float* xr = x + (size_t)row * NPIX;

    float acc[NCLS];
#pragma unroll
    for (int k = 0; k < NCLS; ++k) acc[k] = 0.f;

#pragma unroll
    for (int s = 0; s < 6; ++s) {               // 6*32*4 = 768 pixels
        int p = (tx + (s << 5)) << 2;
        float4 xv = *reinterpret_cast<const float4*>(xr + p);
        float4 tv = *reinterpret_cast<const float4*>(&Tl[p]);
        float f0 = __cosf(xv.x + tv.x);
        float f1 = __cosf(xv.y + tv.y);
        float f2 = __cosf(xv.z + tv.z);
        float f3 = __cosf(xv.w + tv.w);
#pragma unroll
        for (int k = 0; k < NCLS; ++k) {
            float4 wv = *reinterpret_cast<const float4*>(&Wl[k * NPIX + p]);
            acc[k] += f0 * wv.x + f1 * wv.y + f2 * wv.z + f3 * wv.w;
        }
    }
    if (tx < 4) {                               // tail: pixels 768..783
        int p = (tx + 192) << 2;
        float4 xv = *reinterpret_cast<const float4*>(xr + p);
        float4 tv = *reinterpret_cast<const float4*>(&Tl[p]);
        float f0 = __cosf(xv.x + tv.x);
        float f1 = __cosf(xv.y + tv.y);
        float f2 = __cosf(xv.z + tv.z);
        float f3 = __cosf(xv.w + tv.w);
#pragma unroll
        for (int k = 0; k < NCLS; ++k) {
            float4 wv = *reinterpret_cast<const float4*>(&Wl[k * NPIX + p]);
            acc[k] += f0 * wv.x + f1 * wv.y + f2 * wv.z + f3 * wv.w;
        }
    }

    // ---- 32-lane reduction (stays inside each row's lane group) ----
#pragma unroll
    for (int k = 0; k < NCLS; ++k) {
        float v = acc[k];
        v += __shfl_xor(v, 1);
        v += __shfl_xor(v, 2);
        v += __shfl_xor(v, 4);
        v += __shfl_xor(v, 8);
        v += __shfl_xor(v, 16);
        acc[k] = v;
    }

    if (tx == 0) {
        float logits[NCLS];
        float m = -1e30f;
#pragma unroll
        for (int k = 0; k < NCLS; ++k) {
            logits[k] = acc[k] + bias[k];
            m = fmaxf(m, logits[k]);
        }
        float sum = 0.f;
#pragma unroll
        for (int k = 0; k < NCLS; ++k) sum += expf(logits[k] - m);
        float lse = m + logf(sum);
#pragma unroll
        for (int k = 0; k < NCLS; ++k) out[row * NCLS + k] = logits[k] - lse;
    }
}

extern "C" void kernel_launch(void* const* d_in, const int* in_sizes, int n_in,
                              void* d_out, int out_size, void* d_ws, size_t ws_size,
                              hipStream_t stream) {
    const float* x     = (const float*)d_in[0];
    const float* theta = (const float*)d_in[1];
    const float* W     = (const float*)d_in[2];
    const float* bias  = (const float*)d_in[3];
    float* out = (float*)d_out;

    int B = in_sizes[0] / NPIX;          // 8192
    int grid = B / ROWS;                 // 1024 blocks, 16 waves/CU
    quanv_fused_kernel<<<grid, BLOCK, 0, stream>>>(x, theta, W, bias, out);
}

// Round 7
// 79.060 us; speedup vs baseline: 1.1657x; 1.0231x over previous
//
#include <hip/hip_runtime.h>
#include <math.h>

#define NPIX 784
#define NCLS 10
#define ROWS 16           // rows per block (8 lane-groups x 2 rows)
#define BLOCK 256

// Circuit identity: all gates are RY (no entanglers); RY on one wire compose
// additively, so <Z_w> = cos(x_w + sum_l theta[l][w]).
// feats[f], f = patch*4 + w; wire w reads pixel (2pr + (w>>1), 2pc + (w&1)).
// W stays in original f-layout in LDS (straight float4 copy, no permute);
// x is read in patch order (two float2 loads per patch per row).
__global__ __launch_bounds__(256)
void quanv_fused_kernel(const float* __restrict__ x,
                        const float* __restrict__ theta,
                        const float* __restrict__ W,
                        const float* __restrict__ bias,
                        float* __restrict__ out) {
    __shared__ float Wl[NCLS * NPIX];   // 30.6 KB, original layout
    int tid = threadIdx.x;

    // ---- stage W: pure vectorized copy ----
    const float4* W4 = reinterpret_cast<const float4*>(W);
    float4* Wl4 = reinterpret_cast<float4*>(Wl);
    for (int i = tid; i < (NCLS * NPIX) / 4; i += BLOCK) Wl4[i] = W4[i];

    // per-wire angle offsets (L1-cached scalar reads)
    float t0 = theta[0] + theta[4] + theta[8];
    float t1 = theta[1] + theta[5] + theta[9];
    float t2 = theta[2] + theta[6] + theta[10];
    float t3 = theta[3] + theta[7] + theta[11];
    __syncthreads();

    int tx = tid & 31;
    int g  = tid >> 5;                      // 0..7
    int row0 = blockIdx.x * ROWS + g * 2;
    const float* xr0 = x + (size_t)row0 * NPIX;
    const float* xr1 = xr0 + NPIX;

    float acc0[NCLS], acc1[NCLS];
#pragma unroll
    for (int k = 0; k < NCLS; ++k) { acc0[k] = 0.f; acc1[k] = 0.f; }

#pragma unroll
    for (int s = 0; s < 7; ++s) {           // 196 patches: 6 full + 4-lane tail
        int p = tx + (s << 5);
        bool active = (s < 6) | (tx < 4);
        if (active) {
            int pr = p / 14;
            int pc = p - pr * 14;
            int off0 = pr * 56 + pc * 2;    // pixel idx of (2pr, 2pc)
            int off1 = off0 + 28;           // row 2pr+1
            float2 a0 = *reinterpret_cast<const float2*>(xr0 + off0);
            float2 b0 = *reinterpret_cast<const float2*>(xr0 + off1);
            float2 a1 = *reinterpret_cast<const float2*>(xr1 + off0);
            float2 b1 = *reinterpret_cast<const float2*>(xr1 + off1);
            float f00 = __cosf(a0.x + t0), f01 = __cosf(a0.y + t1);
            float f02 = __cosf(b0.x + t2), f03 = __cosf(b0.y + t3);
            float f10 = __cosf(a1.x + t0), f11 = __cosf(a1.y + t1);
            float f12 = __cosf(b1.x + t2), f13 = __cosf(b1.y + t3);
#pragma unroll
            for (int k = 0; k < NCLS; ++k) {
                float4 wv = *reinterpret_cast<const float4*>(&Wl[k * NPIX + (p << 2)]);
                acc0[k] += f00 * wv.x + f01 * wv.y + f02 * wv.z + f03 * wv.w;
                acc1[k] += f10 * wv.x + f11 * wv.y + f12 * wv.z + f13 * wv.w;
            }
        }
    }

    // ---- 32-lane reduction (xor stays inside each row's lane group) ----
#pragma unroll
    for (int k = 0; k < NCLS; ++k) {
        float v0 = acc0[k], v1 = acc1[k];
        v0 += __shfl_xor(v0, 1);  v1 += __shfl_xor(v1, 1);
        v0 += __shfl_xor(v0, 2);  v1 += __shfl_xor(v1, 2);
        v0 += __shfl_xor(v0, 4);  v1 += __shfl_xor(v1, 4);
        v0 += __shfl_xor(v0, 8);  v1 += __shfl_xor(v1, 8);
        v0 += __shfl_xor(v0, 16); v1 += __shfl_xor(v1, 16);
        acc0[k] = v0; acc1[k] = v1;
    }

    // lane 0 -> row0, lane 16 -> row1 (both hold the full sums)
    if (tx == 0 || tx == 16) {
        const float* a = (tx == 0) ? acc0 : acc1;
        int row = (tx == 0) ? row0 : row0 + 1;
        float logits[NCLS];
        float m = -1e30f;
#pragma unroll
        for (int k = 0; k < NCLS; ++k) {
            logits[k] = a[k] + bias[k];
            m = fmaxf(m, logits[k]);
        }
        float sum = 0.f;
#pragma unroll
        for (int k = 0; k < NCLS; ++k) sum += expf(logits[k] - m);
        float lse = m + logf(sum);
#pragma unroll
        for (int k = 0; k < NCLS; ++k) out[row * NCLS + k] = logits[k] - lse;
    }
}

extern "C" void kernel_launch(void* const* d_in, const int* in_sizes, int n_in,
                              void* d_out, int out_size, void* d_ws, size_t ws_size,
                              hipStream_t stream) {
    const float* x     = (const float*)d_in[0];
    const float* theta = (const float*)d_in[1];
    const float* W     = (const float*)d_in[2];
    const float* bias  = (const float*)d_in[3];
    float* out = (float*)d_out;

    int B = in_sizes[0] / NPIX;          // 8192
    int grid = B / ROWS;                 // 512 blocks
    quanv_fused_kernel<<<grid, BLOCK, 0, stream>>>(x, theta, W, bias, out);
}